// Round 2
// baseline (534.039 us; speedup 1.0000x reference)
//
#include <hip/hip_runtime.h>
#include <hip/hip_bf16.h>

// Problem constants
// x2d: (16, 64, 128, 128) f32   -> replication pad (1,2,1,2) -> 131x131
// conv 3x3 VALID, 64->256 ch    -> proj_map (16, 256, 129, 129)
// x3d: (16, 8, 16, 64, 64) f32  -> zeropad3d(1), max depth, mean ch -> (16,1,66,66)
// bilinear resize half-pixel    -> g (16,1,129,129)
// out = mean_{h,w} clip(proj*g, 0, 6)  -> (16, 256)

typedef __bf16 bf16x8_t __attribute__((ext_vector_type(8)));
typedef float  f32x4    __attribute__((ext_vector_type(4)));

#define ROWB     16768          // 131 cols * 64 ch * 2B, bytes per padded row (ch-last)
#define XPT_IMG  (131 * ROWB)   // 2,196,608 B per batch image

// ---------------------------------------------------------------------------
// K0: zero the output accumulator (d_out is poisoned 0xAA before every launch)
__global__ void k_zero(float* __restrict__ out) {
    int t = blockIdx.x * 256 + threadIdx.x;
    if (t < 16 * 256) out[t] = 0.0f;
}

// ---------------------------------------------------------------------------
// K1: x2d (b,c,h,w) f32 -> xpT (b, r(131), col(131), ch(64)) bf16,
// replication-padded, XOR-swizzled within each 128B channel block:
//   byte within row = col*128 + ((ch*2) ^ ((col&7)<<4))
__global__ void k_transpose(const float* __restrict__ x2d, char* __restrict__ xpT) {
    int t = blockIdx.x * 256 + threadIdx.x;
    if (t >= 16 * 131 * 131) return;
    int col = t % 131;
    int r   = (t / 131) % 131;
    int b   = t / (131 * 131);
    int h = min(max(r   - 1, 0), 127);
    int w = min(max(col - 1, 0), 127);
    const float* src = x2d + ((size_t)b * 64 * 128 + h) * 128 + w; // + c*16384
    char* dst = xpT + (size_t)b * XPT_IMG + r * ROWB + col * 128;
    int sw = (col & 7) << 4;
    #pragma unroll
    for (int c8 = 0; c8 < 8; ++c8) {
        bf16x8_t v;
        #pragma unroll
        for (int e = 0; e < 8; ++e) {
            v[e] = (__bf16)src[(size_t)(c8 * 8 + e) * 16384];
        }
        *(bf16x8_t*)(dst + ((c8 * 16) ^ sw)) = v;
    }
}

// ---------------------------------------------------------------------------
// K2: W_proj (256, 576) f32, torch k-order (c*9 + tap) -> B-fragment layout:
// Bfrag[kk][nf][lane] = 8 bf16, k = kk*32 + (lane>>4)*8 + e, n = nf*16 + (lane&15)
// with our K order k = tap*64 + c  (kk = tap*2 + kc, c = kc*32 + (lane>>4)*8 + e)
__global__ void k_bfrag(const float* __restrict__ Wp, char* __restrict__ Bfrag) {
    int t = blockIdx.x * 256 + threadIdx.x;
    if (t >= 18 * 16 * 64) return;
    int lane = t & 63;
    int nf   = (t >> 6) & 15;
    int kk   = t >> 10;
    int tap  = kk >> 1;
    int cb   = (kk & 1) * 32 + ((lane >> 4) << 3);
    int n    = nf * 16 + (lane & 15);
    bf16x8_t v;
    #pragma unroll
    for (int e = 0; e < 8; ++e)
        v[e] = (__bf16)Wp[n * 576 + (cb + e) * 9 + tap];
    *(bf16x8_t*)(Bfrag + (size_t)t * 16) = v;
}

// ---------------------------------------------------------------------------
// K3: gating 66x66: border = 0 (zero pad), interior = mean_c max(0, max_d x3d)
__global__ void k_gating(const float* __restrict__ x3d, float* __restrict__ g66) {
    int t = blockIdx.x * 256 + threadIdx.x;
    if (t >= 16 * 66 * 66) return;
    int x = t % 66;
    int y = (t / 66) % 66;
    int b = t / (66 * 66);
    float outv = 0.0f;
    if (x > 0 && x < 65 && y > 0 && y < 65) {
        float s = 0.0f;
        #pragma unroll
        for (int c = 0; c < 8; ++c) {
            float m = 0.0f;  // zero depth-pad planes participate in max
            #pragma unroll
            for (int d = 0; d < 16; ++d) {
                float v = x3d[(size_t)((b * 8 + c) * 16 + d) * 4096 + (y - 1) * 64 + (x - 1)];
                m = fmaxf(m, v);
            }
            s += m;
        }
        outv = s * 0.125f;
    }
    g66[t] = outv;
}

// ---------------------------------------------------------------------------
// K4: bilinear resize 66x66 -> 129x129, half-pixel centers, edge clamp
__global__ void k_resize(const float* __restrict__ g66, float* __restrict__ g129) {
    int t = blockIdx.x * 256 + threadIdx.x;
    if (t >= 16 * 129 * 129) return;
    int j = t % 129;
    int i = (t / 129) % 129;
    int b = t / (129 * 129);
    const float sc = 66.0f / 129.0f;
    float sy = (i + 0.5f) * sc - 0.5f;
    float sx = (j + 0.5f) * sc - 0.5f;
    float y0f = floorf(sy), x0f = floorf(sx);
    float fy = sy - y0f, fx = sx - x0f;
    int y0 = (int)y0f, x0 = (int)x0f;
    int y0c = min(max(y0, 0), 65), y1c = min(max(y0 + 1, 0), 65);
    int x0c = min(max(x0, 0), 65), x1c = min(max(x0 + 1, 0), 65);
    const float* g = g66 + b * 66 * 66;
    float v = (1.0f - fy) * ((1.0f - fx) * g[y0c * 66 + x0c] + fx * g[y0c * 66 + x1c])
            +         fy  * ((1.0f - fx) * g[y1c * 66 + x0c] + fx * g[y1c * 66 + x1c]);
    g129[t] = v;
}

// ---------------------------------------------------------------------------
// K5: main fused conv + gate + relu6 + global average pool.
// One block per (batch, group of 3 output rows). Ring of 4 LDS row-slots:
// stage rows 0..2, then per output row r prefetch padded row r+3 (overlapped
// with compute of row r). 8 waves; each wave owns 2 N-frags (N=256 total).
// M = 129 (9x16 frags), K = 576 (9 taps x 2 chunks of 32).
__global__ __launch_bounds__(512, 4) void k_conv(
    const char* __restrict__ xpT, const char* __restrict__ Bfrag,
    const float* __restrict__ g129, const float* __restrict__ bias,
    float* __restrict__ out)
{
    __shared__ uint4 smem4[4 * ROWB / 16];   // 4 row slots, 67,072 B
    __shared__ float gld[3][132];
    char* smem = (char*)smem4;

    const int y0   = blockIdx.x * 3;         // 43 groups * 3 = 129 rows exactly
    const int b    = blockIdx.y;
    const int tid  = threadIdx.x;
    const int lane = tid & 63;
    const int w    = tid >> 6;               // wave 0..7
    const int l15  = lane & 15;
    const int lhi  = lane >> 4;

    const char* gsrc = xpT + (size_t)b * XPT_IMG + (size_t)y0 * ROWB;

    // ---- stage one padded row rj (0..4) into ring slot rj&3 (linear copy;
    // swizzle is pre-applied in global memory)
    #define STAGE_ROW(rj) do {                                                  \
        const char* _s = gsrc + (rj) * ROWB;                                    \
        char* _d = smem + ((rj) & 3) * ROWB;                                    \
        for (int i = w; i < 17; i += 8) {                                       \
            int _off = i * 1024;                                                \
            if (_off + lane * 16 < ROWB)                                        \
                __builtin_amdgcn_global_load_lds(                               \
                    (const __attribute__((address_space(1))) void*)(_s + _off + lane * 16), \
                    (__attribute__((address_space(3))) void*)(_d + _off),       \
                    16, 0, 0);                                                  \
        }                                                                       \
    } while (0)

    STAGE_ROW(0);
    STAGE_ROW(1);
    STAGE_ROW(2);
    // preload 3 rows of gate values
    for (int t = tid; t < 3 * 129; t += 512) {
        int rr = t / 129, xx = t - rr * 129;
        gld[rr][xx] = g129[((b * 129) + y0 + rr) * 129 + xx];
    }

    float bval[2];
    #pragma unroll
    for (int nf = 0; nf < 2; ++nf)
        bval[nf] = bias[w * 32 + nf * 16 + l15];

    float s[2] = {0.f, 0.f};

    for (int r = 0; r < 3; ++r) {
        __syncthreads();                     // drains vmcnt: rows <= r+2 staged & visible
        if (r < 2) STAGE_ROW(r + 3);         // overwrites slot of row r-1 (compute done)

        f32x4 acc[9][2];
        #pragma unroll
        for (int mf = 0; mf < 9; ++mf) {
            acc[mf][0] = (f32x4){0.f, 0.f, 0.f, 0.f};
            acc[mf][1] = (f32x4){0.f, 0.f, 0.f, 0.f};
        }

        const int sb0 = ((r + 0) & 3) * ROWB;
        const int sb1 = ((r + 1) & 3) * ROWB;
        const int sb2 = ((r + 2) & 3) * ROWB;
        const int sb[3] = {sb0, sb1, sb2};

        #pragma unroll
        for (int tap = 0; tap < 9; ++tap) {
            const int ki = tap / 3;
            const int kj = tap - ki * 3;
            #pragma unroll
            for (int kc = 0; kc < 2; ++kc) {
                const int kk = tap * 2 + kc;
                bf16x8_t bfr[2];
                #pragma unroll
                for (int nf = 0; nf < 2; ++nf)
                    bfr[nf] = *(const bf16x8_t*)(Bfrag +
                        ((size_t)(kk * 16 + (w * 2 + nf)) * 64 + lane) * 16);
                const int chx = kc << 6;
                #pragma unroll
                for (int mf = 0; mf < 9; ++mf) {
                    int col = mf * 16 + l15 + kj;
                    col = min(col, 130);     // pad-tail guard (only discarded m affected)
                    int off = sb[ki] + col * 128 +
                              ((((col & 7) << 4) ^ (lhi << 4)) ^ chx);
                    bf16x8_t a = *(const bf16x8_t*)(smem + off);
                    acc[mf][0] = __builtin_amdgcn_mfma_f32_16x16x32_bf16(
                        a, bfr[0], acc[mf][0], 0, 0, 0);
                    acc[mf][1] = __builtin_amdgcn_mfma_f32_16x16x32_bf16(
                        a, bfr[1], acc[mf][1], 0, 0, 0);
                }
            }
        }

        // ---- per-row epilogue: bias, gate, relu6, accumulate spatial sum
        #pragma unroll
        for (int mf = 0; mf < 9; ++mf) {
            #pragma unroll
            for (int rr = 0; rr < 4; ++rr) {
                int x = mf * 16 + (lhi << 2) + rr;   // D row m
                if (x < 129) {
                    float gv = gld[r][x];
                    #pragma unroll
                    for (int nf = 0; nf < 2; ++nf) {
                        float v = (acc[mf][nf][rr] + bval[nf]) * gv;
                        v = fminf(fmaxf(v, 0.0f), 6.0f);
                        s[nf] += v;
                    }
                }
            }
        }
    }

    // ---- final reduce across lanes (sum over lhi groups) + atomic accumulate
    #pragma unroll
    for (int nf = 0; nf < 2; ++nf) {
        s[nf] += __shfl_xor(s[nf], 16);
        s[nf] += __shfl_xor(s[nf], 32);
    }
    if (lane < 16) {
        #pragma unroll
        for (int nf = 0; nf < 2; ++nf)
            atomicAdd(&out[b * 256 + w * 32 + nf * 16 + lane],
                      s[nf] * (1.0f / 16641.0f));
    }
    #undef STAGE_ROW
}

// ---------------------------------------------------------------------------
extern "C" void kernel_launch(void* const* d_in, const int* in_sizes, int n_in,
                              void* d_out, int out_size, void* d_ws, size_t ws_size,
                              hipStream_t stream) {
    (void)in_sizes; (void)n_in; (void)out_size; (void)ws_size;
    const float* x2d = (const float*)d_in[0];
    const float* x3d = (const float*)d_in[1];
    const float* Wp  = (const float*)d_in[2];
    const float* bp  = (const float*)d_in[3];
    float* out = (float*)d_out;
    char*  ws  = (char*)d_ws;

    // workspace layout (all 16B aligned)
    char*  xpT   = ws;                                    // 16*131*16768 = 35,137,536 B
    char*  Bfrag = ws + (size_t)16 * XPT_IMG;             // 294,912 B
    float* g66   = (float*)(Bfrag + 294912);              // 278,784 B
    float* g129  = (float*)((char*)g66 + 278784);         // 1,065,024 B

    k_zero     <<<16,   256, 0, stream>>>(out);
    k_transpose<<<(16 * 131 * 131 + 255) / 256, 256, 0, stream>>>(x2d, xpT);
    k_bfrag    <<<72,   256, 0, stream>>>(Wp, Bfrag);
    k_gating   <<<(16 * 66 * 66 + 255) / 256, 256, 0, stream>>>(x3d, g66);
    k_resize   <<<(16 * 129 * 129 + 255) / 256, 256, 0, stream>>>(g66, g129);

    dim3 grid(43, 16);
    k_conv<<<grid, 512, 0, stream>>>(xpT, Bfrag, g129, bp, out);
}

// Round 5
// 386.643 us; speedup vs baseline: 1.3812x; 1.3812x over previous
//
#include <hip/hip_runtime.h>
#include <hip/hip_bf16.h>

// x2d: (16, 64, 128, 128) f32   -> replication pad (1,2,1,2) -> 131x131
// conv 3x3 VALID, 64->256 ch    -> proj_map (16, 256, 129, 129)
// x3d: (16, 8, 16, 64, 64) f32  -> zeropad3d(1), max depth, mean ch -> (16,1,66,66)
// bilinear resize half-pixel    -> g (16,1,129,129)
// out = mean_{h,w} clip(proj*g, 0, 6)  -> (16, 256)

typedef __bf16 bf16x8_t __attribute__((ext_vector_type(8)));
typedef float  f32x4    __attribute__((ext_vector_type(4)));

#define ROWB     16768          // 131 cols * 64 ch * 2B per padded row (ch-last)
#define XPT_IMG  (131 * ROWB)

// ---------------------------------------------------------------------------
__global__ void k_zero(float* __restrict__ out) {
    int t = blockIdx.x * 256 + threadIdx.x;
    if (t < 16 * 256) out[t] = 0.0f;
}

// ---------------------------------------------------------------------------
// K1: x2d (b,c,h,w) f32 -> xpT (b, r, col, ch) bf16, replication-padded,
// XOR-swizzled: byte in row = col*128 + ((ch*2) ^ ((col&7)<<4)).
// LDS-tiled: coalesced 256B reads, conflict-free LDS, coalesced 1KB writes.
__global__ __launch_bounds__(256) void k_transpose(const float* __restrict__ x2d,
                                                   char* __restrict__ xpT) {
    __shared__ float tile[128][65];      // [w][c], +1 pad -> conflict-free
    const int r = blockIdx.x;            // padded row 0..130
    const int b = blockIdx.y;
    const int h = min(max(r - 1, 0), 127);
    const float* src = x2d + ((size_t)b * 64 * 128 + h) * 128;  // + c*16384 + w
    const int tw = threadIdx.x & 63;
    const int tc = threadIdx.x >> 6;     // 0..3
    #pragma unroll
    for (int c = tc; c < 64; c += 4) {
        tile[tw]      [c] = src[(size_t)c * 16384 + tw];
        tile[tw + 64] [c] = src[(size_t)c * 16384 + tw + 64];
    }
    __syncthreads();
    char* dst = xpT + (size_t)b * XPT_IMG + (size_t)r * ROWB;
    for (int item = threadIdx.x; item < 131 * 8; item += 256) {
        int c8  = item & 7;              // channel chunk (8 bf16 = 16B)
        int col = item >> 3;             // 0..130
        int w   = min(max(col - 1, 0), 127);
        int sw  = (col & 7) << 4;
        bf16x8_t v;
        #pragma unroll
        for (int e = 0; e < 8; ++e) v[e] = (__bf16)tile[w][c8 * 8 + e];
        *(bf16x8_t*)(dst + col * 128 + ((c8 * 16) ^ sw)) = v;
    }
}

// ---------------------------------------------------------------------------
// K2: W_proj (256, 576) f32, k-order (c*9+tap) -> B-fragments:
// Bfrag[kk][nf][lane] = 8 bf16; k = kk*32 + (lane>>4)*8 + e, n = nf*16 + (lane&15)
__global__ void k_bfrag(const float* __restrict__ Wp, char* __restrict__ Bfrag) {
    int t = blockIdx.x * 256 + threadIdx.x;
    if (t >= 18 * 16 * 64) return;
    int lane = t & 63;
    int nf   = (t >> 6) & 15;
    int kk   = t >> 10;
    int tap  = kk >> 1;
    int cb   = (kk & 1) * 32 + ((lane >> 4) << 3);
    int n    = nf * 16 + (lane & 15);
    bf16x8_t v;
    #pragma unroll
    for (int e = 0; e < 8; ++e)
        v[e] = (__bf16)Wp[n * 576 + (cb + e) * 9 + tap];
    *(bf16x8_t*)(Bfrag + (size_t)t * 16) = v;
}

// ---------------------------------------------------------------------------
// K3: interior gating gi[b][64][64] = mean_c max(0, max_d x3d[..]) (float4 path)
__global__ void k_gating(const float* __restrict__ x3d, float* __restrict__ gi) {
    const int t  = threadIdx.x;
    const int xg = t & 15;                       // float4 index: x = 4*xg..
    const int y  = blockIdx.x * 16 + (t >> 4);   // 0..63
    const int b  = blockIdx.y;
    const float* base = x3d + (size_t)b * 8 * 16 * 4096 + y * 64 + xg * 4;
    float4 s = {0.f, 0.f, 0.f, 0.f};
    #pragma unroll
    for (int c = 0; c < 8; ++c) {
        float4 m = {0.f, 0.f, 0.f, 0.f};         // zero depth-pad joins the max
        #pragma unroll
        for (int d = 0; d < 16; ++d) {
            float4 v = *(const float4*)(base + (size_t)(c * 16 + d) * 4096);
            m.x = fmaxf(m.x, v.x); m.y = fmaxf(m.y, v.y);
            m.z = fmaxf(m.z, v.z); m.w = fmaxf(m.w, v.w);
        }
        s.x += m.x; s.y += m.y; s.z += m.z; s.w += m.w;
    }
    s.x *= 0.125f; s.y *= 0.125f; s.z *= 0.125f; s.w *= 0.125f;
    *(float4*)(gi + ((size_t)(b * 64 + y) * 64 + xg * 4)) = s;
}

// ---------------------------------------------------------------------------
// K4: bilinear 66x66 (conceptual, border=0, interior=gi) -> 129x129
__device__ __forceinline__ float g66_fetch(const float* __restrict__ gi,
                                           int b, int y, int x) {
    if (y < 1 || y > 64 || x < 1 || x > 64) return 0.0f;
    return gi[((size_t)(b * 64) + (y - 1)) * 64 + (x - 1)];
}

__global__ void k_resize(const float* __restrict__ gi, float* __restrict__ g129) {
    int t = blockIdx.x * 256 + threadIdx.x;
    if (t >= 16 * 129 * 129) return;
    int j = t % 129;
    int i = (t / 129) % 129;
    int b = t / (129 * 129);
    const float sc = 66.0f / 129.0f;
    float sy = (i + 0.5f) * sc - 0.5f;
    float sx = (j + 0.5f) * sc - 0.5f;
    float y0f = floorf(sy), x0f = floorf(sx);
    float fy = sy - y0f, fx = sx - x0f;
    int y0 = (int)y0f, x0 = (int)x0f;
    int y0c = min(max(y0, 0), 65), y1c = min(max(y0 + 1, 0), 65);
    int x0c = min(max(x0, 0), 65), x1c = min(max(x0 + 1, 0), 65);
    float v = (1.0f - fy) * ((1.0f - fx) * g66_fetch(gi, b, y0c, x0c)
                           +         fx  * g66_fetch(gi, b, y0c, x1c))
            +         fy  * ((1.0f - fx) * g66_fetch(gi, b, y1c, x0c)
                           +         fx  * g66_fetch(gi, b, y1c, x1c));
    g129[t] = v;
}

// ---------------------------------------------------------------------------
// K5: fused conv + gate + relu6 + GAP.
// Block = (batch, 3 output rows). 256 threads / 4 waves; each wave 4 N-frags.
// Ring of 4 LDS row-slots: stage rows 0..2, per row r prefetch row r+3
// (overlaps compute). B-fragments double-buffered in registers.
__global__ __launch_bounds__(256, 2) void k_conv(
    const char* __restrict__ xpT, const char* __restrict__ Bfrag,
    const float* __restrict__ g129, const float* __restrict__ bias,
    float* __restrict__ out)
{
    __shared__ uint4 smem4[4 * ROWB / 16];   // 67,072 B
    __shared__ float gld[3][132];
    char* smem = (char*)smem4;

    const int y0   = blockIdx.x * 3;         // 43*3 = 129 rows exactly
    const int b    = blockIdx.y;
    const int tid  = threadIdx.x;
    const int lane = tid & 63;
    const int w    = tid >> 6;               // wave 0..3
    const int l15  = lane & 15;
    const int lhi  = lane >> 4;

    const char* gsrc = xpT + (size_t)b * XPT_IMG + (size_t)y0 * ROWB;

    #define STAGE_ROW(rj) do {                                                  \
        const char* _s = gsrc + (rj) * ROWB;                                    \
        char* _d = smem + ((rj) & 3) * ROWB;                                    \
        for (int i = w; i < 17; i += 4) {                                       \
            int _off = i * 1024;                                                \
            if (_off + lane * 16 < ROWB)                                        \
                __builtin_amdgcn_global_load_lds(                               \
                    (const __attribute__((address_space(1))) void*)(_s + _off + lane * 16), \
                    (__attribute__((address_space(3))) void*)(_d + _off),       \
                    16, 0, 0);                                                  \
        }                                                                       \
    } while (0)

    STAGE_ROW(0);
    STAGE_ROW(1);
    STAGE_ROW(2);
    for (int t2 = tid; t2 < 3 * 129; t2 += 256) {
        int rr = t2 / 129, xx = t2 - rr * 129;
        gld[rr][xx] = g129[((b * 129) + y0 + rr) * 129 + xx];
    }

    float bval[4];
    #pragma unroll
    for (int nf = 0; nf < 4; ++nf)
        bval[nf] = bias[w * 64 + nf * 16 + l15];

    // B-fragment register double-buffer (B is row-invariant; carry across rows)
    bf16x8_t bcur[4];
    #pragma unroll
    for (int nf = 0; nf < 4; ++nf)
        bcur[nf] = *(const bf16x8_t*)(Bfrag +
            ((size_t)(0 * 16 + (w * 4 + nf)) * 64 + lane) * 16);

    float s[4] = {0.f, 0.f, 0.f, 0.f};

    for (int r = 0; r < 3; ++r) {
        __syncthreads();                 // drains vmcnt: rows <= r+2 visible
        if (r < 2) STAGE_ROW(r + 3);     // overwrite slot of row r-1 (done)

        f32x4 acc[9][4];
        #pragma unroll
        for (int mf = 0; mf < 9; ++mf)
            #pragma unroll
            for (int nf = 0; nf < 4; ++nf)
                acc[mf][nf] = (f32x4){0.f, 0.f, 0.f, 0.f};

        const int sb[3] = {((r + 0) & 3) * ROWB, ((r + 1) & 3) * ROWB,
                           ((r + 2) & 3) * ROWB};

        #pragma unroll
        for (int kk = 0; kk < 18; ++kk) {
            const int tap = kk >> 1;
            const int kc  = kk & 1;
            const int ki  = tap / 3;
            const int kj  = tap - ki * 3;
            const int kkn = (kk + 1) % 18;       // compile-time (unrolled)
            bf16x8_t bnxt[4];
            #pragma unroll
            for (int nf = 0; nf < 4; ++nf)
                bnxt[nf] = *(const bf16x8_t*)(Bfrag +
                    ((size_t)(kkn * 16 + (w * 4 + nf)) * 64 + lane) * 16);
            const int chx = kc << 6;
            #pragma unroll
            for (int mf = 0; mf < 9; ++mf) {
                int col = mf * 16 + l15 + kj;
                col = min(col, 130);             // pad-tail guard
                int off = sb[ki] + col * 128 +
                          ((((col & 7) << 4) ^ (lhi << 4)) ^ chx);
                bf16x8_t a = *(const bf16x8_t*)(smem + off);
                #pragma unroll
                for (int nf = 0; nf < 4; ++nf)
                    acc[mf][nf] = __builtin_amdgcn_mfma_f32_16x16x32_bf16(
                        a, bcur[nf], acc[mf][nf], 0, 0, 0);
            }
            #pragma unroll
            for (int nf = 0; nf < 4; ++nf) bcur[nf] = bnxt[nf];
        }

        // per-row epilogue: bias, gate, relu6, spatial partial sum
        #pragma unroll
        for (int mf = 0; mf < 9; ++mf) {
            #pragma unroll
            for (int rr = 0; rr < 4; ++rr) {
                int x = mf * 16 + (lhi << 2) + rr;   // D row m
                if (x < 129) {
                    float gv = gld[r][x];
                    #pragma unroll
                    for (int nf = 0; nf < 4; ++nf) {
                        float v = (acc[mf][nf][rr] + bval[nf]) * gv;
                        v = fminf(fmaxf(v, 0.0f), 6.0f);
                        s[nf] += v;
                    }
                }
            }
        }
    }

    #pragma unroll
    for (int nf = 0; nf < 4; ++nf) {
        s[nf] += __shfl_xor(s[nf], 16);
        s[nf] += __shfl_xor(s[nf], 32);
    }
    if (lane < 16) {
        #pragma unroll
        for (int nf = 0; nf < 4; ++nf)
            atomicAdd(&out[b * 256 + w * 64 + nf * 16 + lane],
                      s[nf] * (1.0f / 16641.0f));
    }
    #undef STAGE_ROW
}

// ---------------------------------------------------------------------------
extern "C" void kernel_launch(void* const* d_in, const int* in_sizes, int n_in,
                              void* d_out, int out_size, void* d_ws, size_t ws_size,
                              hipStream_t stream) {
    (void)in_sizes; (void)n_in; (void)out_size; (void)ws_size;
    const float* x2d = (const float*)d_in[0];
    const float* x3d = (const float*)d_in[1];
    const float* Wp  = (const float*)d_in[2];
    const float* bp  = (const float*)d_in[3];
    float* out = (float*)d_out;
    char*  ws  = (char*)d_ws;

    char*  xpT   = ws;                                    // 35,137,536 B
    char*  Bfrag = ws + (size_t)16 * XPT_IMG;             // 294,912 B
    float* gi    = (float*)(Bfrag + 294912);              // 262,144 B
    float* g129  = (float*)((char*)gi + 262144);          // 1,065,024 B

    k_zero     <<<16, 256, 0, stream>>>(out);
    k_transpose<<<dim3(131, 16), 256, 0, stream>>>(x2d, xpT);
    k_bfrag    <<<72, 256, 0, stream>>>(Wp, Bfrag);
    k_gating   <<<dim3(4, 16), 256, 0, stream>>>(x3d, gi);
    k_resize   <<<(16 * 129 * 129 + 255) / 256, 256, 0, stream>>>(gi, g129);

    dim3 grid(43, 16);
    k_conv<<<grid, 256, 0, stream>>>(xpT, Bfrag, g129, bp, out);
}

// Round 6
// 272.421 us; speedup vs baseline: 1.9603x; 1.4193x over previous
//
#include <hip/hip_runtime.h>
#include <hip/hip_bf16.h>

// x2d: (16, 64, 128, 128) f32   -> replication pad (1,2,1,2) -> 131x131
// conv 3x3 VALID, 64->256 ch    -> proj_map (16, 256, 129, 129)
// x3d: (16, 8, 16, 64, 64) f32  -> zeropad3d(1), max depth, mean ch -> (16,1,66,66)
// bilinear resize half-pixel    -> g (16,1,129,129)
// out = mean_{h,w} clip(proj*g, 0, 6)  -> (16, 256)

typedef __bf16 bf16x8_t __attribute__((ext_vector_type(8)));
typedef float  f32x4    __attribute__((ext_vector_type(4)));

#define ROWB     16768          // 131 cols * 64 ch * 2B per padded row (ch-last)
#define XPT_IMG  (131 * ROWB)

// ---------------------------------------------------------------------------
// K1: x2d (b,c,h,w) f32 -> xpT (b, r, col, ch) bf16, replication-padded,
// XOR-swizzled: byte in row = col*128 + ((ch*2) ^ ((col&7)<<4)).
// LDS-tiled: coalesced 256B reads, conflict-free LDS, coalesced 1KB writes.
__global__ __launch_bounds__(256) void k_transpose(const float* __restrict__ x2d,
                                                   char* __restrict__ xpT) {
    __shared__ float tile[128][65];      // [w][c], +1 pad -> conflict-free
    const int r = blockIdx.x;            // padded row 0..130
    const int b = blockIdx.y;
    const int h = min(max(r - 1, 0), 127);
    const float* src = x2d + ((size_t)b * 64 * 128 + h) * 128;  // + c*16384 + w
    const int tw = threadIdx.x & 63;
    const int tc = threadIdx.x >> 6;     // 0..3
    #pragma unroll
    for (int c = tc; c < 64; c += 4) {
        tile[tw]      [c] = src[(size_t)c * 16384 + tw];
        tile[tw + 64] [c] = src[(size_t)c * 16384 + tw + 64];
    }
    __syncthreads();
    char* dst = xpT + (size_t)b * XPT_IMG + (size_t)r * ROWB;
    for (int item = threadIdx.x; item < 131 * 8; item += 256) {
        int c8  = item & 7;              // channel chunk (8 bf16 = 16B)
        int col = item >> 3;             // 0..130
        int w   = min(max(col - 1, 0), 127);
        int sw  = (col & 7) << 4;
        bf16x8_t v;
        #pragma unroll
        for (int e = 0; e < 8; ++e) v[e] = (__bf16)tile[w][c8 * 8 + e];
        *(bf16x8_t*)(dst + col * 128 + ((c8 * 16) ^ sw)) = v;
    }
}

// ---------------------------------------------------------------------------
// K2: W_proj (256, 576) f32, k-order (c*9+tap) -> B-fragments; also zeroes out
// (d_out is poisoned 0xAA before every launch).
// Bfrag[kk][nf][lane] = 8 bf16; k = kk*32 + (lane>>4)*8 + e, n = nf*16 + (lane&15)
__global__ void k_bfrag(const float* __restrict__ Wp, char* __restrict__ Bfrag,
                        float* __restrict__ out) {
    int t = blockIdx.x * 256 + threadIdx.x;
    if (t < 16 * 256) out[t] = 0.0f;
    if (t >= 18 * 16 * 64) return;
    int lane = t & 63;
    int nf   = (t >> 6) & 15;
    int kk   = t >> 10;
    int tap  = kk >> 1;
    int cb   = (kk & 1) * 32 + ((lane >> 4) << 3);
    int n    = nf * 16 + (lane & 15);
    bf16x8_t v;
    #pragma unroll
    for (int e = 0; e < 8; ++e)
        v[e] = (__bf16)Wp[n * 576 + (cb + e) * 9 + tap];
    *(bf16x8_t*)(Bfrag + (size_t)t * 16) = v;
}

// ---------------------------------------------------------------------------
// K3: interior gating gi[b][64][64] = mean_c max(0, max_d x3d[..]) (float4 path)
__global__ void k_gating(const float* __restrict__ x3d, float* __restrict__ gi) {
    const int t  = threadIdx.x;
    const int xg = t & 15;                       // float4 index: x = 4*xg..
    const int y  = blockIdx.x * 16 + (t >> 4);   // 0..63
    const int b  = blockIdx.y;
    const float* base = x3d + (size_t)b * 8 * 16 * 4096 + y * 64 + xg * 4;
    float4 s = {0.f, 0.f, 0.f, 0.f};
    #pragma unroll
    for (int c = 0; c < 8; ++c) {
        float4 m = {0.f, 0.f, 0.f, 0.f};         // zero depth-pad joins the max
        #pragma unroll
        for (int d = 0; d < 16; ++d) {
            float4 v = *(const float4*)(base + (size_t)(c * 16 + d) * 4096);
            m.x = fmaxf(m.x, v.x); m.y = fmaxf(m.y, v.y);
            m.z = fmaxf(m.z, v.z); m.w = fmaxf(m.w, v.w);
        }
        s.x += m.x; s.y += m.y; s.z += m.z; s.w += m.w;
    }
    s.x *= 0.125f; s.y *= 0.125f; s.z *= 0.125f; s.w *= 0.125f;
    *(float4*)(gi + ((size_t)(b * 64 + y) * 64 + xg * 4)) = s;
}

// ---------------------------------------------------------------------------
// conceptual 66x66 gate (zero border, interior = gi)
__device__ __forceinline__ float g66_fetch(const float* __restrict__ gi,
                                           int b, int y, int x) {
    if (y < 1 || y > 64 || x < 1 || x > 64) return 0.0f;
    return gi[((size_t)(b * 64) + (y - 1)) * 64 + (x - 1)];
}

// ---------------------------------------------------------------------------
// K5: fused conv + gate(inline bilinear) + relu6 + GAP.
// Block = (batch, 3 output rows). 256 threads / 4 waves; each wave 4 N-frags.
// Ring of 4 LDS row-slots: stage rows 0..2, per row r prefetch row r+3
// (overlaps compute). A-reads use one base + immediate offsets (mf 0..7);
// only mf=8 carries the col clamp (its garbage lanes land in D rows >=129,
// which the epilogue discards).
__global__ __launch_bounds__(256) void k_conv(
    const char* __restrict__ xpT, const char* __restrict__ Bfrag,
    const float* __restrict__ gi, const float* __restrict__ bias,
    float* __restrict__ out)
{
    __shared__ uint4 smem4[4 * ROWB / 16];   // 67,072 B
    __shared__ float gld[3][132];
    char* smem = (char*)smem4;

    const int y0   = blockIdx.x * 3;         // 43*3 = 129 rows exactly
    const int b    = blockIdx.y;
    const int tid  = threadIdx.x;
    const int lane = tid & 63;
    const int w    = tid >> 6;               // wave 0..3
    const int l15  = lane & 15;
    const int lhi  = lane >> 4;

    const char* gsrc = xpT + (size_t)b * XPT_IMG + (size_t)y0 * ROWB;

    #define STAGE_ROW(rj) do {                                                  \
        const char* _s = gsrc + (rj) * ROWB;                                    \
        char* _d = smem + ((rj) & 3) * ROWB;                                    \
        for (int i = w; i < 17; i += 4) {                                       \
            int _off = i * 1024;                                                \
            if (_off + lane * 16 < ROWB)                                        \
                __builtin_amdgcn_global_load_lds(                               \
                    (const __attribute__((address_space(1))) void*)(_s + _off + lane * 16), \
                    (__attribute__((address_space(3))) void*)(_d + _off),       \
                    16, 0, 0);                                                  \
        }                                                                       \
    } while (0)

    STAGE_ROW(0);
    STAGE_ROW(1);
    STAGE_ROW(2);

    // inline bilinear resize (66x66 zero-border map -> rows y0..y0+2 of 129x129)
    for (int t2 = tid; t2 < 3 * 129; t2 += 256) {
        int rr = t2 / 129, xx = t2 - rr * 129;
        int i  = y0 + rr;
        const float sc = 66.0f / 129.0f;
        float sy = (i  + 0.5f) * sc - 0.5f;
        float sx = (xx + 0.5f) * sc - 0.5f;
        float y0f = floorf(sy), x0f = floorf(sx);
        float fy = sy - y0f, fx = sx - x0f;
        int yy0 = (int)y0f, xx0 = (int)x0f;
        int y0c = min(max(yy0, 0), 65), y1c = min(max(yy0 + 1, 0), 65);
        int x0c = min(max(xx0, 0), 65), x1c = min(max(xx0 + 1, 0), 65);
        gld[rr][xx] =
            (1.0f - fy) * ((1.0f - fx) * g66_fetch(gi, b, y0c, x0c)
                         +         fx  * g66_fetch(gi, b, y0c, x1c))
          +         fy  * ((1.0f - fx) * g66_fetch(gi, b, y1c, x0c)
                         +         fx  * g66_fetch(gi, b, y1c, x1c));
    }

    float bval[4];
    #pragma unroll
    for (int nf = 0; nf < 4; ++nf)
        bval[nf] = bias[w * 64 + nf * 16 + l15];

    const char* bptr = Bfrag + (size_t)(w * 4) * 1024 + (size_t)lane * 16;

    float s[4] = {0.f, 0.f, 0.f, 0.f};

    for (int r = 0; r < 3; ++r) {
        __syncthreads();                 // drains vmcnt: rows <= r+2 visible
        if (r < 2) STAGE_ROW(r + 3);     // overwrite slot of row r-1 (done)

        f32x4 acc[9][4];
        #pragma unroll
        for (int mf = 0; mf < 9; ++mf)
            #pragma unroll
            for (int nf = 0; nf < 4; ++nf)
                acc[mf][nf] = (f32x4){0.f, 0.f, 0.f, 0.f};

        const int sb[3] = {((r + 0) & 3) * ROWB, ((r + 1) & 3) * ROWB,
                           ((r + 2) & 3) * ROWB};

        #pragma unroll
        for (int kk = 0; kk < 18; ++kk) {
            const int tap = kk >> 1;
            const int kc  = kk & 1;
            const int ki  = tap / 3;
            const int kj  = tap - ki * 3;
            bf16x8_t bfr[4];
            #pragma unroll
            for (int nf = 0; nf < 4; ++nf)
                bfr[nf] = *(const bf16x8_t*)(bptr + (size_t)kk * 16384 + nf * 1024);
            // base col for mf=0; swizzle term is mf-invariant ((col+16)&7 == col&7)
            const int cb  = l15 + kj;
            const int swz = (((cb & 7) << 4) ^ (lhi << 4)) ^ (kc << 6);
            const char* abase = smem + (sb[ki] + cb * 128 + swz);
            #pragma unroll
            for (int mf = 0; mf < 8; ++mf) {
                bf16x8_t a = *(const bf16x8_t*)(abase + mf * 2048);
                #pragma unroll
                for (int nf = 0; nf < 4; ++nf)
                    acc[mf][nf] = __builtin_amdgcn_mfma_f32_16x16x32_bf16(
                        a, bfr[nf], acc[mf][nf], 0, 0, 0);
            }
            {   // mf = 8: col clamp (only discarded D-rows >= 129 affected)
                int col8 = min(128 + cb, 130);
                bf16x8_t a = *(const bf16x8_t*)(smem + sb[ki] + col8 * 128 + swz);
                #pragma unroll
                for (int nf = 0; nf < 4; ++nf)
                    acc[8][nf] = __builtin_amdgcn_mfma_f32_16x16x32_bf16(
                        a, bfr[nf], acc[8][nf], 0, 0, 0);
            }
        }

        // per-row epilogue: bias, gate, relu6, spatial partial sum
        #pragma unroll
        for (int mf = 0; mf < 9; ++mf) {
            #pragma unroll
            for (int rr = 0; rr < 4; ++rr) {
                int x = mf * 16 + (lhi << 2) + rr;   // D row m
                if (x < 129) {
                    float gv = gld[r][x];
                    #pragma unroll
                    for (int nf = 0; nf < 4; ++nf) {
                        float v = (acc[mf][nf][rr] + bval[nf]) * gv;
                        v = fminf(fmaxf(v, 0.0f), 6.0f);
                        s[nf] += v;
                    }
                }
            }
        }
    }

    #pragma unroll
    for (int nf = 0; nf < 4; ++nf) {
        s[nf] += __shfl_xor(s[nf], 16);
        s[nf] += __shfl_xor(s[nf], 32);
    }
    if (lane < 16) {
        #pragma unroll
        for (int nf = 0; nf < 4; ++nf)
            atomicAdd(&out[b * 256 + w * 64 + nf * 16 + lane],
                      s[nf] * (1.0f / 16641.0f));
    }
    #undef STAGE_ROW
}

// ---------------------------------------------------------------------------
extern "C" void kernel_launch(void* const* d_in, const int* in_sizes, int n_in,
                              void* d_out, int out_size, void* d_ws, size_t ws_size,
                              hipStream_t stream) {
    (void)in_sizes; (void)n_in; (void)out_size; (void)ws_size;
    const float* x2d = (const float*)d_in[0];
    const float* x3d = (const float*)d_in[1];
    const float* Wp  = (const float*)d_in[2];
    const float* bp  = (const float*)d_in[3];
    float* out = (float*)d_out;
    char*  ws  = (char*)d_ws;

    char*  xpT   = ws;                                    // 35,137,536 B
    char*  Bfrag = ws + (size_t)16 * XPT_IMG;             // 294,912 B
    float* gi    = (float*)(Bfrag + 294912);              // 262,144 B

    k_bfrag    <<<72, 256, 0, stream>>>(Wp, Bfrag, out);  // also zeroes out
    k_transpose<<<dim3(131, 16), 256, 0, stream>>>(x2d, xpT);
    k_gating   <<<dim3(4, 16), 256, 0, stream>>>(x3d, gi);

    dim3 grid(43, 16);
    k_conv<<<grid, 256, 0, stream>>>(xpT, Bfrag, gi, bp, out);
}

// Round 8
// 231.973 us; speedup vs baseline: 2.3022x; 1.1744x over previous
//
#include <hip/hip_runtime.h>
#include <hip/hip_bf16.h>

// x2d: (16, 64, 128, 128) f32   -> replication pad (1,2,1,2) -> 131x131
// conv 3x3 VALID, 64->256 ch    -> proj_map (16, 256, 129, 129)
// x3d: (16, 8, 16, 64, 64) f32  -> zeropad3d(1), max depth, mean ch -> (16,1,66,66)
// bilinear resize half-pixel    -> g (16,1,129,129)
// out = mean_{h,w} clip(proj*g, 0, 6)  -> (16, 256)

typedef __bf16 bf16x8_t __attribute__((ext_vector_type(8)));
typedef float  f32x4    __attribute__((ext_vector_type(4)));

#define ROWB     16768          // 131 cols * 64 ch * 2B per padded row (ch-last)
#define XPT_IMG  (131 * ROWB)

// ---------------------------------------------------------------------------
// K1: x2d (b,c,h,w) f32 -> xpT (b, r, col, ch) bf16, replication-padded,
// XOR-swizzled: byte in row = col*128 + ((ch*2) ^ ((col&7)<<4)).
// LDS-tiled: coalesced 256B reads, conflict-free LDS, coalesced 1KB writes.
__global__ __launch_bounds__(256) void k_transpose(const float* __restrict__ x2d,
                                                   char* __restrict__ xpT) {
    __shared__ float tile[128][65];      // [w][c], +1 pad -> conflict-free
    const int r = blockIdx.x;            // padded row 0..130
    const int b = blockIdx.y;
    const int h = min(max(r - 1, 0), 127);
    const float* src = x2d + ((size_t)b * 64 * 128 + h) * 128;  // + c*16384 + w
    const int tw = threadIdx.x & 63;
    const int tc = threadIdx.x >> 6;     // 0..3
    #pragma unroll
    for (int c = tc; c < 64; c += 4) {
        tile[tw]      [c] = src[(size_t)c * 16384 + tw];
        tile[tw + 64] [c] = src[(size_t)c * 16384 + tw + 64];
    }
    __syncthreads();
    char* dst = xpT + (size_t)b * XPT_IMG + (size_t)r * ROWB;
    for (int item = threadIdx.x; item < 131 * 8; item += 256) {
        int c8  = item & 7;              // channel chunk (8 bf16 = 16B)
        int col = item >> 3;             // 0..130
        int w   = min(max(col - 1, 0), 127);
        int sw  = (col & 7) << 4;
        bf16x8_t v;
        #pragma unroll
        for (int e = 0; e < 8; ++e) v[e] = (__bf16)tile[w][c8 * 8 + e];
        *(bf16x8_t*)(dst + col * 128 + ((c8 * 16) ^ sw)) = v;
    }
}

// ---------------------------------------------------------------------------
// K2: W_proj (256, 576) f32, k-order (c*9+tap) -> B-fragments; also zeroes out
// (d_out is poisoned 0xAA before every launch).
// Bfrag[kk][nf][lane] = 8 bf16; k = kk*32 + (lane>>4)*8 + e, n = nf*16 + (lane&15)
__global__ void k_bfrag(const float* __restrict__ Wp, char* __restrict__ Bfrag,
                        float* __restrict__ out) {
    int t = blockIdx.x * 256 + threadIdx.x;
    if (t < 16 * 256) out[t] = 0.0f;
    if (t >= 18 * 16 * 64) return;
    int lane = t & 63;
    int nf   = (t >> 6) & 15;
    int kk   = t >> 10;
    int tap  = kk >> 1;
    int cb   = (kk & 1) * 32 + ((lane >> 4) << 3);
    int n    = nf * 16 + (lane & 15);
    bf16x8_t v;
    #pragma unroll
    for (int e = 0; e < 8; ++e)
        v[e] = (__bf16)Wp[n * 576 + (cb + e) * 9 + tap];
    *(bf16x8_t*)(Bfrag + (size_t)t * 16) = v;
}

// ---------------------------------------------------------------------------
// K3: interior gating gi[b][64][64] = mean_c max(0, max_d x3d[..]) (float4 path)
__global__ void k_gating(const float* __restrict__ x3d, float* __restrict__ gi) {
    const int t  = threadIdx.x;
    const int xg = t & 15;                       // float4 index: x = 4*xg..
    const int y  = blockIdx.x * 16 + (t >> 4);   // 0..63
    const int b  = blockIdx.y;
    const float* base = x3d + (size_t)b * 8 * 16 * 4096 + y * 64 + xg * 4;
    float4 s = {0.f, 0.f, 0.f, 0.f};
    #pragma unroll
    for (int c = 0; c < 8; ++c) {
        float4 m = {0.f, 0.f, 0.f, 0.f};         // zero depth-pad joins the max
        #pragma unroll
        for (int d = 0; d < 16; ++d) {
            float4 v = *(const float4*)(base + (size_t)(c * 16 + d) * 4096);
            m.x = fmaxf(m.x, v.x); m.y = fmaxf(m.y, v.y);
            m.z = fmaxf(m.z, v.z); m.w = fmaxf(m.w, v.w);
        }
        s.x += m.x; s.y += m.y; s.z += m.z; s.w += m.w;
    }
    s.x *= 0.125f; s.y *= 0.125f; s.z *= 0.125f; s.w *= 0.125f;
    *(float4*)(gi + ((size_t)(b * 64 + y) * 64 + xg * 4)) = s;
}

// ---------------------------------------------------------------------------
// conceptual 66x66 gate (zero border, interior = gi)
__device__ __forceinline__ float g66_fetch(const float* __restrict__ gi,
                                           int b, int y, int x) {
    if (y < 1 || y > 64 || x < 1 || x > 64) return 0.0f;
    return gi[((size_t)(b * 64) + (y - 1)) * 64 + (x - 1)];
}

// ---------------------------------------------------------------------------
// K5: fused conv + gate(inline bilinear) + relu6 + GAP.
// Block = (batch, 3 output rows). 512 threads / 8 waves; each wave 2 N-frags
// (acc[9][2] = 72 VGPR -> no spill, target <=128 total for 2 blocks/CU).
// Ring of 4 LDS row-slots; runtime tap loop (NOT fully unrolled -> bounded
// live ranges; R6's full unroll caused the 256-VGPR spill).
__global__ __launch_bounds__(512) void k_conv(
    const char* __restrict__ xpT, const char* __restrict__ Bfrag,
    const float* __restrict__ gi, const float* __restrict__ bias,
    float* __restrict__ out)
{
    __shared__ uint4 smem4[4 * ROWB / 16];   // 67,072 B
    __shared__ float gld[3][132];
    char* smem = (char*)smem4;

    const int y0   = blockIdx.x * 3;         // 43*3 = 129 rows exactly
    const int b    = blockIdx.y;
    const int tid  = threadIdx.x;
    const int lane = tid & 63;
    const int w    = tid >> 6;               // wave 0..7
    const int l15  = lane & 15;
    const int lhi  = lane >> 4;

    const char* gsrc = xpT + (size_t)b * XPT_IMG + (size_t)y0 * ROWB;

    #define STAGE_ROW(rj) do {                                                  \
        const char* _s = gsrc + (rj) * ROWB;                                    \
        char* _d = smem + ((rj) & 3) * ROWB;                                    \
        for (int i = w; i < 17; i += 8) {                                       \
            int _off = i * 1024;                                                \
            if (_off + lane * 16 < ROWB)                                        \
                __builtin_amdgcn_global_load_lds(                               \
                    (const __attribute__((address_space(1))) void*)(_s + _off + lane * 16), \
                    (__attribute__((address_space(3))) void*)(_d + _off),       \
                    16, 0, 0);                                                  \
        }                                                                       \
    } while (0)

    STAGE_ROW(0);
    STAGE_ROW(1);
    STAGE_ROW(2);

    // inline bilinear resize (66x66 zero-border map -> rows y0..y0+2 of 129x129)
    for (int t2 = tid; t2 < 3 * 129; t2 += 512) {
        int rr = t2 / 129, xx = t2 - rr * 129;
        int i  = y0 + rr;
        const float sc = 66.0f / 129.0f;
        float sy = (i  + 0.5f) * sc - 0.5f;
        float sx = (xx + 0.5f) * sc - 0.5f;
        float y0f = floorf(sy), x0f = floorf(sx);
        float fy = sy - y0f, fx = sx - x0f;
        int yy0 = (int)y0f, xx0 = (int)x0f;
        int y0c = min(max(yy0, 0), 65), y1c = min(max(yy0 + 1, 0), 65);
        int x0c = min(max(xx0, 0), 65), x1c = min(max(xx0 + 1, 0), 65);
        gld[rr][xx] =
            (1.0f - fy) * ((1.0f - fx) * g66_fetch(gi, b, y0c, x0c)
                         +         fx  * g66_fetch(gi, b, y0c, x1c))
          +         fy  * ((1.0f - fx) * g66_fetch(gi, b, y1c, x0c)
                         +         fx  * g66_fetch(gi, b, y1c, x1c));
    }

    float bval[2];
    #pragma unroll
    for (int nf = 0; nf < 2; ++nf)
        bval[nf] = bias[w * 32 + nf * 16 + l15];

    const char* bptr = Bfrag + (size_t)(w * 2) * 1024 + (size_t)lane * 16;

    float s[2] = {0.f, 0.f};

    for (int r = 0; r < 3; ++r) {
        __syncthreads();                 // drains vmcnt: rows <= r+2 visible
        if (r < 2) STAGE_ROW(r + 3);     // prefetch row r+3 (in flight over compute)

        f32x4 acc[9][2];
        #pragma unroll
        for (int mf = 0; mf < 9; ++mf) {
            acc[mf][0] = (f32x4){0.f, 0.f, 0.f, 0.f};
            acc[mf][1] = (f32x4){0.f, 0.f, 0.f, 0.f};
        }

        for (int tap = 0; tap < 9; ++tap) {          // runtime loop: bounded VGPR
            const int ki    = tap / 3;
            const int kj    = tap - ki * 3;
            const int sbase = ((r + ki) & 3) * ROWB;  // arithmetic, no array idx
            #pragma unroll
            for (int kc = 0; kc < 2; ++kc) {
                const int kk = tap * 2 + kc;
                bf16x8_t bfr[2];
                bfr[0] = *(const bf16x8_t*)(bptr + (size_t)kk * 16384);
                bfr[1] = *(const bf16x8_t*)(bptr + (size_t)kk * 16384 + 1024);
                // base col for mf=0; swizzle term is mf-invariant ((col+16)&7==col&7)
                const int cb  = l15 + kj;
                const int swz = (((cb & 7) << 4) ^ (lhi << 4)) ^ (kc << 6);
                const char* abase = smem + sbase + cb * 128 + swz;
                #pragma unroll
                for (int mf = 0; mf < 8; ++mf) {
                    bf16x8_t a = *(const bf16x8_t*)(abase + mf * 2048);
                    acc[mf][0] = __builtin_amdgcn_mfma_f32_16x16x32_bf16(
                        a, bfr[0], acc[mf][0], 0, 0, 0);
                    acc[mf][1] = __builtin_amdgcn_mfma_f32_16x16x32_bf16(
                        a, bfr[1], acc[mf][1], 0, 0, 0);
                }
                {   // mf = 8: col clamp (garbage lanes land in discarded D rows >=129)
                    int col8 = min(128 + cb, 130);
                    bf16x8_t a = *(const bf16x8_t*)(smem + sbase + col8 * 128 + swz);
                    acc[8][0] = __builtin_amdgcn_mfma_f32_16x16x32_bf16(
                        a, bfr[0], acc[8][0], 0, 0, 0);
                    acc[8][1] = __builtin_amdgcn_mfma_f32_16x16x32_bf16(
                        a, bfr[1], acc[8][1], 0, 0, 0);
                }
            }
        }

        // per-row epilogue: bias, gate, relu6, spatial partial sum
        #pragma unroll
        for (int mf = 0; mf < 9; ++mf) {
            #pragma unroll
            for (int rr = 0; rr < 4; ++rr) {
                int x = mf * 16 + (lhi << 2) + rr;   // D row m
                if (x < 129) {
                    float gv = gld[r][x];
                    #pragma unroll
                    for (int nf = 0; nf < 2; ++nf) {
                        float v = (acc[mf][nf][rr] + bval[nf]) * gv;
                        v = fminf(fmaxf(v, 0.0f), 6.0f);
                        s[nf] += v;
                    }
                }
            }
        }
    }

    #pragma unroll
    for (int nf = 0; nf < 2; ++nf) {
        s[nf] += __shfl_xor(s[nf], 16);
        s[nf] += __shfl_xor(s[nf], 32);
    }
    if (lane < 16) {
        #pragma unroll
        for (int nf = 0; nf < 2; ++nf)
            atomicAdd(&out[b * 256 + w * 32 + nf * 16 + lane],
                      s[nf] * (1.0f / 16641.0f));
    }
    #undef STAGE_ROW
}

// ---------------------------------------------------------------------------
extern "C" void kernel_launch(void* const* d_in, const int* in_sizes, int n_in,
                              void* d_out, int out_size, void* d_ws, size_t ws_size,
                              hipStream_t stream) {
    (void)in_sizes; (void)n_in; (void)out_size; (void)ws_size;
    const float* x2d = (const float*)d_in[0];
    const float* x3d = (const float*)d_in[1];
    const float* Wp  = (const float*)d_in[2];
    const float* bp  = (const float*)d_in[3];
    float* out = (float*)d_out;
    char*  ws  = (char*)d_ws;

    char*  xpT   = ws;                                    // 35,137,536 B
    char*  Bfrag = ws + (size_t)16 * XPT_IMG;             // 294,912 B
    float* gi    = (float*)(Bfrag + 294912);              // 262,144 B

    k_bfrag    <<<72, 256, 0, stream>>>(Wp, Bfrag, out);  // also zeroes out
    k_transpose<<<dim3(131, 16), 256, 0, stream>>>(x2d, xpT);
    k_gating   <<<dim3(4, 16), 256, 0, stream>>>(x3d, gi);

    dim3 grid(43, 16);
    k_conv<<<grid, 512, 0, stream>>>(xpT, Bfrag, gi, bp, out);
}